// Round 1
// baseline (574.238 us; speedup 1.0000x reference)
//
#include <hip/hip_runtime.h>

#define T_SEQ 100
#define C_EMB 16
#define DCOL  256

// d_ws float layout:
//   [0, 256)          : M'[k][c] = 0.25*log2(e) * sum_d WQ[k][d]*WK[c][d]  (16x16)
//   [256, 256+4096)   : WV[c][j] = sum_h Wv[c][h]*Wdv[h][j]                (16x256)
//   [4352, ...)       : Z[B*T][16] softmax-weighted x rows (if ws_size allows)

__global__ __launch_bounds__(256) void prep_kernel(
    const float* __restrict__ Wk, const float* __restrict__ Wq,
    const float* __restrict__ Wv, const float* __restrict__ Wdk,
    const float* __restrict__ Wdq, const float* __restrict__ Wdv,
    float* __restrict__ ws)
{
    __shared__ float WQL[16][260];   // padded; rows 1040B apart (16B-aligned)
    __shared__ float WKL[16][260];
    const int tid = threadIdx.x;     // output column d / j (0..255)

    // WQ = Wq@Wdq, WK = Wk@Wdk, WV = Wv@Wdv — register-accumulated over h.
    float aq[16], ak[16], av[16];
    #pragma unroll
    for (int i = 0; i < 16; ++i) { aq[i] = 0.f; ak[i] = 0.f; av[i] = 0.f; }
    for (int h = 0; h < 64; ++h) {
        const float wdq = Wdq[h*256 + tid];   // coalesced
        const float wdk = Wdk[h*256 + tid];
        const float wdv = Wdv[h*256 + tid];
        #pragma unroll
        for (int i = 0; i < 16; ++i) {
            aq[i] += Wq[i*64 + h] * wdq;      // uniform scalar operands
            ak[i] += Wk[i*64 + h] * wdk;
            av[i] += Wv[i*64 + h] * wdv;
        }
    }
    #pragma unroll
    for (int i = 0; i < 16; ++i) {
        WQL[i][tid] = aq[i];
        WKL[i][tid] = ak[i];
        ws[256 + i*256 + tid] = av[i];        // WV out
    }
    __syncthreads();

    // M'[k][c] = scale * sum_d WQ[k][d]*WK[c][d]; one thread per element.
    {
        const float scale = 0.25f * 1.4426950408889634f;  // C^-0.5 * log2(e)
        const int k = tid >> 4;
        const int c = tid & 15;
        float acc = 0.f;
        for (int d4 = 0; d4 < 64; ++d4) {
            float4 a = *(const float4*)&WQL[k][4*d4];
            float4 b = *(const float4*)&WKL[c][4*d4];
            acc += a.x*b.x + a.y*b.y + a.z*b.z + a.w*b.w;
        }
        ws[k*16 + c] = acc * scale;
    }
}

// Phase A: per batch, y = x_t @ M', one-pass softmax-weighted sum of x rows.
// Lean register budget (~60 live floats) and 4 parallel FMA chains for the
// score dot (depth 16 -> depth 4+2) so 4 waves/SIMD can cover the latency.
__global__ __launch_bounds__(128) void attn_z_kernel(
    const float* __restrict__ x, const float* __restrict__ ws,
    float* __restrict__ Z, const int zstride)
{
    __shared__ float Xs[T_SEQ * 16];   // this block's x tile (6.4 KB)

    const int b   = blockIdx.x;
    const int tid = threadIdx.x;
    const int t   = tid;            // query row owned by this lane (valid if <100)
    const int wid = tid >> 6;       // wave 0 -> rows 0..63, wave 1 -> rows 64..99

    const float* __restrict__ xb = x + (size_t)b * (T_SEQ * C_EMB);

    for (int i = tid; i < T_SEQ * 4; i += 128)
        ((float4*)Xs)[i] = ((const float4*)xb)[i];
    __syncthreads();

    const int tl = (t < T_SEQ) ? t : (T_SEQ - 1);
    float xt[16];
    #pragma unroll
    for (int i = 0; i < 4; ++i) {
        float4 q = ((const float4*)&Xs[tl * 16])[i];
        xt[4*i+0] = q.x; xt[4*i+1] = q.y; xt[4*i+2] = q.z; xt[4*i+3] = q.w;
    }

    float y[16];
    #pragma unroll
    for (int c = 0; c < 16; ++c) y[c] = 0.f;
    #pragma unroll
    for (int k = 0; k < 16; ++k) {
        const float xk = xt[k];
        #pragma unroll
        for (int c = 0; c < 16; ++c)
            y[c] = fmaf(xk, ws[k*16 + c], y[c]);   // uniform addr -> s_load
    }

    float4 z0 = {0,0,0,0}, z1 = {0,0,0,0}, z2 = {0,0,0,0}, z3 = {0,0,0,0};
    float l = 0.f;

    const int smax = (wid == 0) ? 64 : T_SEQ;  // wave-uniform trip count
    const float4* __restrict__ X4 = (const float4*)Xs;
    for (int s = 0; s < smax; ++s) {
        float4 a0 = X4[s*4+0];                 // LDS broadcast (uniform addr)
        float4 a1 = X4[s*4+1];
        float4 a2 = X4[s*4+2];
        float4 a3 = X4[s*4+3];
        // 4 independent FMA chains, depth 4, then a depth-2 combine.
        float p0 = fmaf(y[ 3], a0.w, fmaf(y[ 2], a0.z, fmaf(y[ 1], a0.y, y[ 0]*a0.x)));
        float p1 = fmaf(y[ 7], a1.w, fmaf(y[ 6], a1.z, fmaf(y[ 5], a1.y, y[ 4]*a1.x)));
        float p2 = fmaf(y[11], a2.w, fmaf(y[10], a2.z, fmaf(y[ 9], a2.y, y[ 8]*a2.x)));
        float p3 = fmaf(y[15], a3.w, fmaf(y[14], a3.z, fmaf(y[13], a3.y, y[12]*a3.x)));
        float sc = (p0 + p1) + (p2 + p3);
        // scores far below exp2 overflow; softmax shift-invariance makes
        // max-subtraction unnecessary in fp32
        float p = __builtin_amdgcn_exp2f(sc);
        p = (s <= t) ? p : 0.f;               // causal mask
        l += p;
        z0.x = fmaf(p, a0.x, z0.x); z0.y = fmaf(p, a0.y, z0.y);
        z0.z = fmaf(p, a0.z, z0.z); z0.w = fmaf(p, a0.w, z0.w);
        z1.x = fmaf(p, a1.x, z1.x); z1.y = fmaf(p, a1.y, z1.y);
        z1.z = fmaf(p, a1.z, z1.z); z1.w = fmaf(p, a1.w, z1.w);
        z2.x = fmaf(p, a2.x, z2.x); z2.y = fmaf(p, a2.y, z2.y);
        z2.z = fmaf(p, a2.z, z2.z); z2.w = fmaf(p, a2.w, z2.w);
        z3.x = fmaf(p, a3.x, z3.x); z3.y = fmaf(p, a3.y, z3.y);
        z3.z = fmaf(p, a3.z, z3.z); z3.w = fmaf(p, a3.w, z3.w);
    }

    if (t < T_SEQ) {
        const float li = __builtin_amdgcn_rcpf(l);
        float* __restrict__ zo = Z + ((size_t)b * T_SEQ + t) * zstride;
        float4 o0 = {z0.x*li, z0.y*li, z0.z*li, z0.w*li};
        float4 o1 = {z1.x*li, z1.y*li, z1.z*li, z1.w*li};
        float4 o2 = {z2.x*li, z2.y*li, z2.z*li, z2.w*li};
        float4 o3 = {z3.x*li, z3.y*li, z3.z*li, z3.w*li};
        ((float4*)zo)[0] = o0; ((float4*)zo)[1] = o1;
        ((float4*)zo)[2] = o2; ((float4*)zo)[3] = o3;
    }
}

// Phase C: out[r][:] = Z[r] @ WV. Pure streaming write kernel.
// One wave per row-iteration: lane j covers cols 4j..4j+3 (1 KB/wave store).
// Z row is wave-uniform -> s_load_dwordx16 + v_fmac with SGPR operand.
__global__ __launch_bounds__(256) void out_kernel(
    const float* __restrict__ Z, const int zstride,
    const float* __restrict__ ws, float* __restrict__ out, const int nrows)
{
    const int lane = threadIdx.x & 63;
    const int gw   = (blockIdx.x << 2) + (threadIdx.x >> 6);  // global wave id
    const int nw   = gridDim.x << 2;

    const float* __restrict__ WVp = ws + 256;
    float4 wv[16];
    #pragma unroll
    for (int c = 0; c < 16; ++c)
        wv[c] = *(const float4*)&WVp[c*256 + 4*lane];   // L2-hot, coalesced

    for (int r = gw; r < nrows; r += nw) {
        const int ru = __builtin_amdgcn_readfirstlane(r);   // certify uniform
        const float* __restrict__ zr = Z + (size_t)ru * zstride;
        float4 acc = {0.f, 0.f, 0.f, 0.f};
        #pragma unroll
        for (int c = 0; c < 16; ++c) {
            const float zc = zr[c];             // SGPR broadcast
            acc.x = fmaf(zc, wv[c].x, acc.x);
            acc.y = fmaf(zc, wv[c].y, acc.y);
            acc.z = fmaf(zc, wv[c].z, acc.z);
            acc.w = fmaf(zc, wv[c].w, acc.w);
        }
        *(float4*)&out[(size_t)ru * DCOL + 4*lane] = acc;   // dwordx4, 1 KB/wave
    }
}

extern "C" void kernel_launch(void* const* d_in, const int* in_sizes, int n_in,
                              void* d_out, int out_size, void* d_ws, size_t ws_size,
                              hipStream_t stream) {
    const float* x   = (const float*)d_in[0];
    const float* Wk  = (const float*)d_in[1];
    const float* Wq  = (const float*)d_in[2];
    const float* Wv  = (const float*)d_in[3];
    const float* Wdk = (const float*)d_in[4];
    const float* Wdq = (const float*)d_in[5];
    const float* Wdv = (const float*)d_in[6];
    float* out = (float*)d_out;
    float* ws  = (float*)d_ws;

    const int B     = in_sizes[0] / (T_SEQ * C_EMB);
    const int nrows = B * T_SEQ;

    prep_kernel<<<1, 256, 0, stream>>>(Wk, Wq, Wv, Wdk, Wdq, Wdv, ws);

    // Z placement: workspace if it fits, else stash in the first 16 columns of
    // each out row (out_kernel reads z before overwriting the row).
    const size_t zoff_floats  = 4352;
    const size_t zneed_bytes  = (zoff_floats + (size_t)nrows * 16) * sizeof(float);
    float* Z;
    int zstride;
    if (ws_size >= zneed_bytes) { Z = ws + zoff_floats; zstride = 16;   }
    else                        { Z = out;              zstride = DCOL; }

    attn_z_kernel<<<B, 128, 0, stream>>>(x, ws, Z, zstride);

    out_kernel<<<2048, 256, 0, stream>>>(Z, zstride, ws, out, nrows);
}

// Round 2
// 557.533 us; speedup vs baseline: 1.0300x; 1.0300x over previous
//
#include <hip/hip_runtime.h>

#define T_SEQ 100
#define C_EMB 16
#define DCOL  256

// d_ws float layout:
//   [0, 256)          : M'[k][c] = 0.25*log2(e) * sum_d WQ[k][d]*WK[c][d]  (16x16)
//   [256, 256+4096)   : WV[c][j] = sum_h Wv[c][h]*Wdv[h][j]                (16x256)
//   [4352, ...)       : Z[B*T][16] softmax-weighted x rows (if ws_size allows)

__global__ __launch_bounds__(256) void prep_kernel(
    const float* __restrict__ Wk, const float* __restrict__ Wq,
    const float* __restrict__ Wv, const float* __restrict__ Wdk,
    const float* __restrict__ Wdq, const float* __restrict__ Wdv,
    float* __restrict__ ws)
{
    __shared__ float WQL[16][260];   // padded; rows 1040B apart (16B-aligned)
    __shared__ float WKL[16][260];
    const int tid = threadIdx.x;     // output column d / j (0..255)

    // WQ = Wq@Wdq, WK = Wk@Wdk, WV = Wv@Wdv — register-accumulated over h.
    float aq[16], ak[16], av[16];
    #pragma unroll
    for (int i = 0; i < 16; ++i) { aq[i] = 0.f; ak[i] = 0.f; av[i] = 0.f; }
    for (int h = 0; h < 64; ++h) {
        const float wdq = Wdq[h*256 + tid];   // coalesced
        const float wdk = Wdk[h*256 + tid];
        const float wdv = Wdv[h*256 + tid];
        #pragma unroll
        for (int i = 0; i < 16; ++i) {
            aq[i] += Wq[i*64 + h] * wdq;      // uniform scalar operands
            ak[i] += Wk[i*64 + h] * wdk;
            av[i] += Wv[i*64 + h] * wdv;
        }
    }
    #pragma unroll
    for (int i = 0; i < 16; ++i) {
        WQL[i][tid] = aq[i];
        WKL[i][tid] = ak[i];
        ws[256 + i*256 + tid] = av[i];        // WV out
    }
    __syncthreads();

    // M'[k][c] = scale * sum_d WQ[k][d]*WK[c][d]; one thread per element.
    {
        const float scale = 0.25f * 1.4426950408889634f;  // C^-0.5 * log2(e)
        const int k = tid >> 4;
        const int c = tid & 15;
        float acc = 0.f;
        for (int d4 = 0; d4 < 64; ++d4) {
            float4 a = *(const float4*)&WQL[k][4*d4];
            float4 b = *(const float4*)&WKL[c][4*d4];
            acc += a.x*b.x + a.y*b.y + a.z*b.z + a.w*b.w;
        }
        ws[k*16 + c] = acc * scale;
    }
}

// Phase A: per batch, y = x_t @ M', one-pass softmax-weighted sum of x rows.
// LDS-FREE: the shared x_s stream is read with wave-uniform global loads
// (compiler scalarizes to s_load / or single 16B L1-hit requests; both
// pipeline deeper than the ds_read chain that stalled the previous version).
__global__ __launch_bounds__(128) void attn_z_kernel(
    const float* __restrict__ x, const float* __restrict__ ws,
    float* __restrict__ Z, const int zstride)
{
    const int b   = blockIdx.x;
    const int tid = threadIdx.x;
    const int t   = tid;            // query row owned by this lane (valid if <100)
    const int wid = tid >> 6;       // wave 0 -> rows 0..63, wave 1 -> rows 64..99

    const float* __restrict__ xb = x + (size_t)b * (T_SEQ * C_EMB);

    // own query row (per-lane vector loads, one-time, L1/L2-hot)
    const int tl = (t < T_SEQ) ? t : (T_SEQ - 1);
    float xt[16];
    #pragma unroll
    for (int i = 0; i < 4; ++i) {
        float4 q = ((const float4*)(xb + tl * 16))[i];
        xt[4*i+0] = q.x; xt[4*i+1] = q.y; xt[4*i+2] = q.z; xt[4*i+3] = q.w;
    }

    float y[16];
    #pragma unroll
    for (int c = 0; c < 16; ++c) y[c] = 0.f;
    #pragma unroll
    for (int k = 0; k < 16; ++k) {
        const float xk = xt[k];
        #pragma unroll
        for (int c = 0; c < 16; ++c)
            y[c] = fmaf(xk, ws[k*16 + c], y[c]);   // uniform addr -> s_load
    }

    float4 z0 = {0,0,0,0}, z1 = {0,0,0,0}, z2 = {0,0,0,0}, z3 = {0,0,0,0};
    float l = 0.f;

    const int smax = (wid == 0) ? 64 : T_SEQ;  // wave-uniform trip count
    const float4* __restrict__ X4 = (const float4*)xb;
    #pragma unroll 2
    for (int s = 0; s < smax; ++s) {
        float4 a0 = X4[s*4+0];                 // wave-uniform global load
        float4 a1 = X4[s*4+1];
        float4 a2 = X4[s*4+2];
        float4 a3 = X4[s*4+3];
        // 4 independent FMA chains, depth 4, then a depth-2 combine.
        float p0 = fmaf(y[ 3], a0.w, fmaf(y[ 2], a0.z, fmaf(y[ 1], a0.y, y[ 0]*a0.x)));
        float p1 = fmaf(y[ 7], a1.w, fmaf(y[ 6], a1.z, fmaf(y[ 5], a1.y, y[ 4]*a1.x)));
        float p2 = fmaf(y[11], a2.w, fmaf(y[10], a2.z, fmaf(y[ 9], a2.y, y[ 8]*a2.x)));
        float p3 = fmaf(y[15], a3.w, fmaf(y[14], a3.z, fmaf(y[13], a3.y, y[12]*a3.x)));
        float sc = (p0 + p1) + (p2 + p3);
        // scores far below exp2 overflow; softmax shift-invariance makes
        // max-subtraction unnecessary in fp32
        float p = __builtin_amdgcn_exp2f(sc);
        p = (s <= t) ? p : 0.f;               // causal mask
        l += p;
        z0.x = fmaf(p, a0.x, z0.x); z0.y = fmaf(p, a0.y, z0.y);
        z0.z = fmaf(p, a0.z, z0.z); z0.w = fmaf(p, a0.w, z0.w);
        z1.x = fmaf(p, a1.x, z1.x); z1.y = fmaf(p, a1.y, z1.y);
        z1.z = fmaf(p, a1.z, z1.z); z1.w = fmaf(p, a1.w, z1.w);
        z2.x = fmaf(p, a2.x, z2.x); z2.y = fmaf(p, a2.y, z2.y);
        z2.z = fmaf(p, a2.z, z2.z); z2.w = fmaf(p, a2.w, z2.w);
        z3.x = fmaf(p, a3.x, z3.x); z3.y = fmaf(p, a3.y, z3.y);
        z3.z = fmaf(p, a3.z, z3.z); z3.w = fmaf(p, a3.w, z3.w);
    }

    if (t < T_SEQ) {
        const float li = __builtin_amdgcn_rcpf(l);
        float* __restrict__ zo = Z + ((size_t)b * T_SEQ + t) * zstride;
        float4 o0 = {z0.x*li, z0.y*li, z0.z*li, z0.w*li};
        float4 o1 = {z1.x*li, z1.y*li, z1.z*li, z1.w*li};
        float4 o2 = {z2.x*li, z2.y*li, z2.z*li, z2.w*li};
        float4 o3 = {z3.x*li, z3.y*li, z3.z*li, z3.w*li};
        ((float4*)zo)[0] = o0; ((float4*)zo)[1] = o1;
        ((float4*)zo)[2] = o2; ((float4*)zo)[3] = o3;
    }
}

// Phase C: out[r][:] = Z[r] @ WV. Pure streaming write kernel.
// One wave per row-iteration: lane j covers cols 4j..4j+3 (1 KB/wave store).
// Z row is wave-uniform -> s_load + v_fmac with SGPR operand.
__global__ __launch_bounds__(256) void out_kernel(
    const float* __restrict__ Z, const int zstride,
    const float* __restrict__ ws, float* __restrict__ out, const int nrows)
{
    const int lane = threadIdx.x & 63;
    const int gw   = (blockIdx.x << 2) + (threadIdx.x >> 6);  // global wave id
    const int nw   = gridDim.x << 2;

    const float* __restrict__ WVp = ws + 256;
    float4 wv[16];
    #pragma unroll
    for (int c = 0; c < 16; ++c)
        wv[c] = *(const float4*)&WVp[c*256 + 4*lane];   // L2-hot, coalesced

    for (int r = gw; r < nrows; r += nw) {
        const int ru = __builtin_amdgcn_readfirstlane(r);   // certify uniform
        const float* __restrict__ zr = Z + (size_t)ru * zstride;
        float4 acc = {0.f, 0.f, 0.f, 0.f};
        #pragma unroll
        for (int c = 0; c < 16; ++c) {
            const float zc = zr[c];             // SGPR broadcast
            acc.x = fmaf(zc, wv[c].x, acc.x);
            acc.y = fmaf(zc, wv[c].y, acc.y);
            acc.z = fmaf(zc, wv[c].z, acc.z);
            acc.w = fmaf(zc, wv[c].w, acc.w);
        }
        *(float4*)&out[(size_t)ru * DCOL + 4*lane] = acc;   // dwordx4, 1 KB/wave
    }
}

extern "C" void kernel_launch(void* const* d_in, const int* in_sizes, int n_in,
                              void* d_out, int out_size, void* d_ws, size_t ws_size,
                              hipStream_t stream) {
    const float* x   = (const float*)d_in[0];
    const float* Wk  = (const float*)d_in[1];
    const float* Wq  = (const float*)d_in[2];
    const float* Wv  = (const float*)d_in[3];
    const float* Wdk = (const float*)d_in[4];
    const float* Wdq = (const float*)d_in[5];
    const float* Wdv = (const float*)d_in[6];
    float* out = (float*)d_out;
    float* ws  = (float*)d_ws;

    const int B     = in_sizes[0] / (T_SEQ * C_EMB);
    const int nrows = B * T_SEQ;

    prep_kernel<<<1, 256, 0, stream>>>(Wk, Wq, Wv, Wdk, Wdq, Wdv, ws);

    // Z placement: workspace if it fits, else stash in the first 16 columns of
    // each out row (out_kernel reads z before overwriting the row).
    const size_t zoff_floats  = 4352;
    const size_t zneed_bytes  = (zoff_floats + (size_t)nrows * 16) * sizeof(float);
    float* Z;
    int zstride;
    if (ws_size >= zneed_bytes) { Z = ws + zoff_floats; zstride = 16;   }
    else                        { Z = out;              zstride = DCOL; }

    attn_z_kernel<<<B, 128, 0, stream>>>(x, ws, Z, zstride);

    out_kernel<<<4096, 256, 0, stream>>>(Z, zstride, ws, out, nrows);
}